// Round 4
// baseline (177.716 us; speedup 1.0000x reference)
//
#include <hip/hip_runtime.h>
#include <math.h>

#define EPSN 1e-4f
#define SEQ 2304

using bf16x8 = __attribute__((ext_vector_type(8))) short;
using f32x4  = __attribute__((ext_vector_type(4))) float;

__device__ inline unsigned short f2bf(float x) {
    union { float f; unsigned u; } c; c.f = x;
    unsigned u = c.u;
    u += 0x7fffu + ((u >> 16) & 1u);
    return (unsigned short)(u >> 16);
}

// ---------------- Kernel 1: weight normalization -> bf16 ----------------
__global__ __launch_bounds__(256) void wnorm_kernel(const float* __restrict__ w_qkv,
                                                    const float* __restrict__ w_out,
                                                    unsigned short* __restrict__ wqb,
                                                    unsigned short* __restrict__ wob) {
    int row = blockIdx.x;
    const float* src;
    unsigned short* dst;
    if (row < 768) { src = w_qkv + row * 256; dst = wqb + row * 256; }
    else           { src = w_out + (row - 768) * 256; dst = wob + (row - 768) * 256; }
    float v = src[threadIdx.x];
    float ss = v * v;
    for (int off = 32; off > 0; off >>= 1) ss += __shfl_down(ss, off, 64);
    __shared__ float red[4];
    __shared__ float scale_s;
    int lane = threadIdx.x & 63, wid = threadIdx.x >> 6;
    if (lane == 0) red[wid] = ss;
    __syncthreads();
    if (threadIdx.x == 0) {
        float t = red[0] + red[1] + red[2] + red[3];
        scale_s = 1.0f / (sqrtf(t) + 16.0f * EPSN);
    }
    __syncthreads();
    dst[threadIdx.x] = f2bf(v * scale_s);
}

// ---------------- Kernel 2: transpose x -> xt[n][s][c] bf16 ----------------
__global__ __launch_bounds__(256) void xt_kernel(const float* __restrict__ x,
                                                 unsigned short* __restrict__ xt) {
    __shared__ __align__(16) unsigned short T[64][80];
    int st = blockIdx.x;   // 0..35
    int ct = blockIdx.y;   // 0..3
    int n  = blockIdx.z;
    int t = threadIdx.x;
#pragma unroll
    for (int p = 0; p < 4; ++p) {
        int e = t + p * 256;
        int c = e >> 4, sv = (e & 15) * 4;
        float4 v = *(const float4*)&x[(size_t)(n * 256 + ct * 64 + c) * SEQ + st * 64 + sv];
        T[sv + 0][c] = f2bf(v.x);
        T[sv + 1][c] = f2bf(v.y);
        T[sv + 2][c] = f2bf(v.z);
        T[sv + 3][c] = f2bf(v.w);
    }
    __syncthreads();
#pragma unroll
    for (int p = 0; p < 2; ++p) {
        int e = t + p * 256;
        int s = e >> 3, cb = (e & 7) * 8;
        uint4 v = *(const uint4*)&T[s][cb];
        *(uint4*)&xt[(size_t)(n * SEQ + st * 64 + s) * 256 + ct * 64 + cb] = v;
    }
}

// ---------------- Kernel 3: fused QKV GEMM + d-normalize ----------------
// grid (8 heads, 36 s-tiles, 2 n); block computes 96x64 output (one head's q,k,v),
// normalizes over d=32 per (which, s), writes qn/kn [nh][s][d], vn [nh][d][s] bf16.
__global__ __launch_bounds__(256) void qkv_fused_kernel(const unsigned short* __restrict__ xt,
                                                        const unsigned short* __restrict__ wqb,
                                                        unsigned short* __restrict__ qn,
                                                        unsigned short* __restrict__ kn,
                                                        unsigned short* __restrict__ vn) {
    __shared__ float Cs[96][65];
    int h  = blockIdx.x;
    int st = blockIdx.y;
    int n  = blockIdx.z;
    int tid = threadIdx.x;
    int wave = tid >> 6, lane = tid & 63;
    int ln = lane & 15, quad = lane >> 4;
    const unsigned short* Abase = wqb + (size_t)(h * 96 + ln) * 256 + quad * 8;
    const unsigned short* Bbase = xt + (size_t)(n * SEQ + st * 64 + wave * 16 + ln) * 256 + quad * 8;
    f32x4 acc[6];
#pragma unroll
    for (int m = 0; m < 6; ++m) acc[m] = (f32x4){0.f, 0.f, 0.f, 0.f};
#pragma unroll
    for (int kc = 0; kc < 8; ++kc) {
        bf16x8 b = *(const bf16x8*)(Bbase + kc * 32);
#pragma unroll
        for (int m = 0; m < 6; ++m) {
            bf16x8 a = *(const bf16x8*)(Abase + (size_t)(m * 16) * 256 + kc * 32);
            acc[m] = __builtin_amdgcn_mfma_f32_16x16x32_bf16(a, b, acc[m], 0, 0, 0);
        }
    }
#pragma unroll
    for (int m = 0; m < 6; ++m)
#pragma unroll
        for (int r = 0; r < 4; ++r)
            Cs[m * 16 + quad * 4 + r][wave * 16 + ln] = acc[m][r];
    __syncthreads();
    if (tid < 192) {
        int sl = tid & 63, wh = tid >> 6;
        int s = st * 64 + sl;
        int nh = n * 8 + h;
        float v[32];
        float ss = 0.f;
#pragma unroll
        for (int d = 0; d < 32; ++d) { v[d] = Cs[3 * d + wh][sl]; ss += v[d] * v[d]; }
        float inv = 1.0f / (EPSN + sqrtf(ss * (1.0f / 32.0f)));
        if (wh == 0) inv *= 0.17677669529663687f;   // fold softmax scale into q
        if (wh == 2) {
            unsigned short* dst = vn + (size_t)nh * 73728 + s;
#pragma unroll
            for (int d = 0; d < 32; ++d) dst[(size_t)d * SEQ] = f2bf(v[d] * inv);
        } else {
            unsigned short* dst = (wh == 1 ? kn : qn) + (size_t)nh * 73728 + (size_t)s * 32;
            unsigned wbuf[16];
#pragma unroll
            for (int j = 0; j < 16; ++j)
                wbuf[j] = (unsigned)f2bf(v[2 * j] * inv) | ((unsigned)f2bf(v[2 * j + 1] * inv) << 16);
#pragma unroll
            for (int j = 0; j < 4; ++j) {
                uint4 t4 = make_uint4(wbuf[4 * j], wbuf[4 * j + 1], wbuf[4 * j + 2], wbuf[4 * j + 3]);
                *(uint4*)(dst + j * 8) = t4;
            }
        }
    }
}

// ---------------- Kernel 4: MFMA flash attention, split-K=3, 1 barrier/iter ----------------
__global__ __launch_bounds__(256) void attn_mfma_kernel(const unsigned short* __restrict__ qn,
                                                        const unsigned short* __restrict__ kn,
                                                        const unsigned short* __restrict__ vn,
                                                        float* __restrict__ Opart,
                                                        float* __restrict__ Lpart) {
    __shared__ __align__(16) unsigned short Ks[2][64][40];
    __shared__ __align__(16) unsigned short Vs[2][32][72];
    __shared__ __align__(16) unsigned short Ps[4][16][72];
    int tid = threadIdx.x;
    int wave = tid >> 6, lane = tid & 63;
    int ln = lane & 15, quad = lane >> 4;
    int qt = blockIdx.x, nh = blockIdx.y, kz = blockIdx.z;
    const unsigned short* Qg = qn + (size_t)nh * 73728;
    const unsigned short* Kg = kn + (size_t)nh * 73728;
    const unsigned short* Vg = vn + (size_t)nh * 73728;

    bf16x8 qf = *(const bf16x8*)(Qg + (size_t)(qt * 64 + wave * 16 + ln) * 32 + quad * 8);
    bf16x8 ones;
#pragma unroll
    for (int i = 0; i < 8; ++i) ones[i] = (short)0x3F80;

    f32x4 o0 = {0.f, 0.f, 0.f, 0.f};
    f32x4 o1 = {0.f, 0.f, 0.f, 0.f};
    f32x4 lac = {0.f, 0.f, 0.f, 0.f};

    int kt0 = kz * 12;
    uint4 kreg = *(const uint4*)(Kg + (size_t)(kt0 * 64) * 32 + tid * 8);
    uint4 vreg = *(const uint4*)(Vg + (size_t)(tid >> 3) * SEQ + kt0 * 64 + (tid & 7) * 8);
    *(uint4*)(&Ks[0][tid >> 2][(tid & 3) * 8]) = kreg;
    *(uint4*)(&Vs[0][tid >> 3][(tid & 7) * 8]) = vreg;

    for (int i = 0; i < 12; ++i) {
        int buf = i & 1;
        if (i + 1 < 12) {   // stage next tile into registers (global only, no LDS)
            int k0n = (kt0 + i + 1) * 64;
            kreg = *(const uint4*)(Kg + (size_t)k0n * 32 + tid * 8);
            vreg = *(const uint4*)(Vg + (size_t)(tid >> 3) * SEQ + k0n + (tid & 7) * 8);
        }
        __syncthreads();   // buf fully written; prev-buf readers done

        const f32x4 zero = {0.f, 0.f, 0.f, 0.f};
#pragma unroll
        for (int c = 0; c < 4; ++c) {
            bf16x8 kf = *(const bf16x8*)(&Ks[buf][c * 16 + ln][quad * 8]);
            f32x4 sc = __builtin_amdgcn_mfma_f32_16x16x32_bf16(qf, kf, zero, 0, 0, 0);
#pragma unroll
            for (int r = 0; r < 4; ++r)
                Ps[wave][quad * 4 + r][c * 16 + ln] = f2bf(__expf(sc[r]));
        }
        // Ps is wave-private: lgkmcnt ordering suffices, no barrier
#pragma unroll
        for (int kc = 0; kc < 2; ++kc) {
            bf16x8 pf = *(const bf16x8*)(&Ps[wave][ln][kc * 32 + quad * 8]);
            bf16x8 v0 = *(const bf16x8*)(&Vs[buf][ln][kc * 32 + quad * 8]);
            bf16x8 v1 = *(const bf16x8*)(&Vs[buf][16 + ln][kc * 32 + quad * 8]);
            lac = __builtin_amdgcn_mfma_f32_16x16x32_bf16(pf, ones, lac, 0, 0, 0);
            o0  = __builtin_amdgcn_mfma_f32_16x16x32_bf16(pf, v0, o0, 0, 0, 0);
            o1  = __builtin_amdgcn_mfma_f32_16x16x32_bf16(pf, v1, o1, 0, 0, 0);
        }
        if (i + 1 < 12) {   // write next buffer after this buf's reads are issued
            *(uint4*)(&Ks[buf ^ 1][tid >> 2][(tid & 3) * 8]) = kreg;
            *(uint4*)(&Vs[buf ^ 1][tid >> 3][(tid & 7) * 8]) = vreg;
        }
    }

    float* Ob = Opart + ((size_t)(kz * 16 + nh) * 36 + qt) * 2048;
    float* Lb = Lpart + ((size_t)(kz * 16 + nh) * 36 + qt) * 64;
#pragma unroll
    for (int r = 0; r < 4; ++r) {
        int ql = wave * 16 + quad * 4 + r;
        Ob[ql * 32 + ln]      = o0[r];
        Ob[ql * 32 + 16 + ln] = o1[r];
        if (ln == 0) Lb[ql] = lac[r];
    }
}

// ---------------- Kernel 5: out GEMM with fused split-K reduce + residual ----------------
__global__ __launch_bounds__(256) void out_fused_kernel(const float* __restrict__ Opart,
                                                        const float* __restrict__ Lpart,
                                                        const unsigned short* __restrict__ wob,
                                                        const float* __restrict__ x,
                                                        float* __restrict__ out) {
    int mt = blockIdx.x;   // 0..3
    int st = blockIdx.y;   // 0..35
    int n  = blockIdx.z;
    int tid = threadIdx.x;
    int wave = tid >> 6, lane = tid & 63;
    int ln = lane & 15, quad = lane >> 4;
    int m0 = mt * 64 + wave * 16;
    const unsigned short* Abase = wob + (size_t)(m0 + ln) * 256 + quad * 8;
    f32x4 acc[4];
#pragma unroll
    for (int c = 0; c < 4; ++c) acc[c] = (f32x4){0.f, 0.f, 0.f, 0.f};
#pragma unroll
    for (int kc = 0; kc < 8; ++kc) {   // k-chunk == head kc
        int nh = n * 8 + kc;
        bf16x8 a = *(const bf16x8*)(Abase + kc * 32);
#pragma unroll
        for (int c = 0; c < 4; ++c) {
            int q = c * 16 + ln;
            float s0[8] = {0.f, 0.f, 0.f, 0.f, 0.f, 0.f, 0.f, 0.f};
            float l = 0.f;
#pragma unroll
            for (int kzi = 0; kzi < 3; ++kzi) {
                size_t slot = (size_t)(kzi * 16 + nh) * 36 + st;
                const float* Ob = Opart + slot * 2048 + q * 32 + quad * 8;
                float4 a0 = *(const float4*)Ob;
                float4 a1 = *(const float4*)(Ob + 4);
                s0[0] += a0.x; s0[1] += a0.y; s0[2] += a0.z; s0[3] += a0.w;
                s0[4] += a1.x; s0[5] += a1.y; s0[6] += a1.z; s0[7] += a1.w;
                l += Lpart[slot * 64 + q];
            }
            float inv = 1.0f / l;
            bf16x8 b;
#pragma unroll
            for (int j = 0; j < 8; ++j) b[j] = (short)f2bf(s0[j] * inv);
            acc[c] = __builtin_amdgcn_mfma_f32_16x16x32_bf16(a, b, acc[c], 0, 0, 0);
        }
    }
    const float c0f = 0.7f * 1.3130643285972254f;
    const float c1f = 0.3f * 1.3130643285972254f;
#pragma unroll
    for (int c = 0; c < 4; ++c)
#pragma unroll
        for (int r = 0; r < 4; ++r) {
            int o = m0 + quad * 4 + r;
            int s = st * 64 + c * 16 + ln;
            size_t idx = (size_t)(n * 256 + o) * SEQ + s;
            out[idx] = c0f * x[idx] + c1f * acc[c][r];
        }
}

extern "C" void kernel_launch(void* const* d_in, const int* in_sizes, int n_in,
                              void* d_out, int out_size, void* d_ws, size_t ws_size,
                              hipStream_t stream) {
    (void)in_sizes; (void)n_in; (void)out_size; (void)ws_size;
    const float* x     = (const float*)d_in[0];
    const float* w_qkv = (const float*)d_in[1];
    const float* w_out = (const float*)d_in[2];
    float* out = (float*)d_out;
    float* ws  = (float*)d_ws;
    // no aliasing needed (ws is large); float offsets:
    unsigned short* wqb = (unsigned short*)(ws);             // 98304 f
    unsigned short* wob = (unsigned short*)(ws + 98304);     // 32768 f
    unsigned short* xt  = (unsigned short*)(ws + 131072);    // 589824 f
    unsigned short* qn  = (unsigned short*)(ws + 720896);    // 589824 f
    unsigned short* kn  = (unsigned short*)(ws + 1310720);   // 589824 f
    unsigned short* vn  = (unsigned short*)(ws + 1900544);   // 589824 f
    float* Opart = ws + 2490368;                             // 48*36*2048 = 3538944 f
    float* Lpart = ws + 6029312;                             // 48*36*64   =  110592 f

    hipLaunchKernelGGL(wnorm_kernel, dim3(1024), dim3(256), 0, stream,
                       w_qkv, w_out, wqb, wob);
    hipLaunchKernelGGL(xt_kernel, dim3(36, 4, 2), dim3(256), 0, stream, x, xt);
    hipLaunchKernelGGL(qkv_fused_kernel, dim3(8, 36, 2), dim3(256), 0, stream,
                       xt, wqb, qn, kn, vn);
    hipLaunchKernelGGL(attn_mfma_kernel, dim3(36, 16, 3), dim3(256), 0, stream,
                       qn, kn, vn, Opart, Lpart);
    hipLaunchKernelGGL(out_fused_kernel, dim3(4, 36, 2), dim3(256), 0, stream,
                       Opart, Lpart, wob, x, out);
}

// Round 5
// 131.220 us; speedup vs baseline: 1.3543x; 1.3543x over previous
//
#include <hip/hip_runtime.h>
#include <math.h>

#define EPSN 1e-4f
#define SEQ 2304

using bf16x8 = __attribute__((ext_vector_type(8))) short;
using f32x4  = __attribute__((ext_vector_type(4))) float;

__device__ inline unsigned short f2bf(float x) {
    union { float f; unsigned u; } c; c.f = x;
    unsigned u = c.u;
    u += 0x7fffu + ((u >> 16) & 1u);
    return (unsigned short)(u >> 16);
}

// ---------------- Kernel 1: prep = weight-norm (blocks 0..1023) + x-transpose ----------------
__global__ __launch_bounds__(256) void prep_kernel(const float* __restrict__ w_qkv,
                                                   const float* __restrict__ w_out,
                                                   const float* __restrict__ x,
                                                   unsigned short* __restrict__ wqb,
                                                   unsigned short* __restrict__ wob,
                                                   unsigned short* __restrict__ xt) {
    __shared__ __align__(16) unsigned short T[64][80];
    __shared__ float red[4];
    __shared__ float scale_s;
    int bid = blockIdx.x;
    if (bid < 1024) {
        // w_eff[o,i] = w[o,i] / (16*EPS + ||w[o]||), stored bf16
        const float* src;
        unsigned short* dst;
        if (bid < 768) { src = w_qkv + bid * 256; dst = wqb + bid * 256; }
        else           { src = w_out + (bid - 768) * 256; dst = wob + (bid - 768) * 256; }
        float v = src[threadIdx.x];
        float ss = v * v;
        for (int off = 32; off > 0; off >>= 1) ss += __shfl_down(ss, off, 64);
        int lane = threadIdx.x & 63, wid = threadIdx.x >> 6;
        if (lane == 0) red[wid] = ss;
        __syncthreads();
        if (threadIdx.x == 0) {
            float t = red[0] + red[1] + red[2] + red[3];
            scale_s = 1.0f / (sqrtf(t) + 16.0f * EPSN);
        }
        __syncthreads();
        dst[threadIdx.x] = f2bf(v * scale_s);
    } else {
        // transpose x[n][c][s] -> xt[n][s][c] bf16
        int e0 = bid - 1024;           // 0..287
        int st = e0 % 36, ct = (e0 / 36) & 3, n = e0 / 144;
        int t = threadIdx.x;
#pragma unroll
        for (int p = 0; p < 4; ++p) {
            int e = t + p * 256;
            int c = e >> 4, sv = (e & 15) * 4;
            float4 v = *(const float4*)&x[(size_t)(n * 256 + ct * 64 + c) * SEQ + st * 64 + sv];
            T[sv + 0][c] = f2bf(v.x);
            T[sv + 1][c] = f2bf(v.y);
            T[sv + 2][c] = f2bf(v.z);
            T[sv + 3][c] = f2bf(v.w);
        }
        __syncthreads();
#pragma unroll
        for (int p = 0; p < 2; ++p) {
            int e = t + p * 256;
            int s = e >> 3, cb = (e & 7) * 8;
            uint4 v = *(const uint4*)&T[s][cb];
            *(uint4*)&xt[(size_t)(n * SEQ + st * 64 + s) * 256 + ct * 64 + cb] = v;
        }
    }
}

// ---------------- Kernel 2: fused QKV GEMM + d-normalize ----------------
// grid (8 heads, 36 s-tiles, 2 n); block computes 96x64 (one head's q,k,v),
// normalizes over d=32, writes qn/kn [nh][s][d], vn [nh][d][s] bf16.
__global__ __launch_bounds__(256) void qkv_fused_kernel(const unsigned short* __restrict__ xt,
                                                        const unsigned short* __restrict__ wqb,
                                                        unsigned short* __restrict__ qn,
                                                        unsigned short* __restrict__ kn,
                                                        unsigned short* __restrict__ vn) {
    __shared__ float Cs[96][65];
    int h  = blockIdx.x;
    int st = blockIdx.y;
    int n  = blockIdx.z;
    int tid = threadIdx.x;
    int wave = tid >> 6, lane = tid & 63;
    int ln = lane & 15, quad = lane >> 4;
    const unsigned short* Abase = wqb + (size_t)(h * 96 + ln) * 256 + quad * 8;
    const unsigned short* Bbase = xt + (size_t)(n * SEQ + st * 64 + wave * 16 + ln) * 256 + quad * 8;
    f32x4 acc[6];
#pragma unroll
    for (int m = 0; m < 6; ++m) acc[m] = (f32x4){0.f, 0.f, 0.f, 0.f};
#pragma unroll
    for (int kc = 0; kc < 8; ++kc) {
        bf16x8 b = *(const bf16x8*)(Bbase + kc * 32);
#pragma unroll
        for (int m = 0; m < 6; ++m) {
            bf16x8 a = *(const bf16x8*)(Abase + (size_t)(m * 16) * 256 + kc * 32);
            acc[m] = __builtin_amdgcn_mfma_f32_16x16x32_bf16(a, b, acc[m], 0, 0, 0);
        }
    }
#pragma unroll
    for (int m = 0; m < 6; ++m)
#pragma unroll
        for (int r = 0; r < 4; ++r)
            Cs[m * 16 + quad * 4 + r][wave * 16 + ln] = acc[m][r];
    __syncthreads();
    if (tid < 192) {
        int sl = tid & 63, wh = tid >> 6;
        int s = st * 64 + sl;
        int nh = n * 8 + h;
        float v[32];
        float ss = 0.f;
#pragma unroll
        for (int d = 0; d < 32; ++d) { v[d] = Cs[3 * d + wh][sl]; ss += v[d] * v[d]; }
        float inv = 1.0f / (EPSN + sqrtf(ss * (1.0f / 32.0f)));
        if (wh == 0) inv *= 0.17677669529663687f;   // fold softmax scale into q
        if (wh == 2) {
            unsigned short* dst = vn + (size_t)nh * 73728 + s;
#pragma unroll
            for (int d = 0; d < 32; ++d) dst[(size_t)d * SEQ] = f2bf(v[d] * inv);
        } else {
            unsigned short* dst = (wh == 1 ? kn : qn) + (size_t)nh * 73728 + (size_t)s * 32;
            unsigned wbuf[16];
#pragma unroll
            for (int j = 0; j < 16; ++j)
                wbuf[j] = (unsigned)f2bf(v[2 * j] * inv) | ((unsigned)f2bf(v[2 * j + 1] * inv) << 16);
#pragma unroll
            for (int j = 0; j < 4; ++j) {
                uint4 t4 = make_uint4(wbuf[4 * j], wbuf[4 * j + 1], wbuf[4 * j + 2], wbuf[4 * j + 3]);
                *(uint4*)(dst + j * 8) = t4;
            }
        }
    }
}

// ---------------- Kernel 3: MFMA flash attention, split-K=3, 1 barrier/iter ----------------
__global__ __launch_bounds__(256) void attn_mfma_kernel(const unsigned short* __restrict__ qn,
                                                        const unsigned short* __restrict__ kn,
                                                        const unsigned short* __restrict__ vn,
                                                        float* __restrict__ Opart,
                                                        float* __restrict__ Lpart) {
    __shared__ __align__(16) unsigned short Ks[2][64][40];
    __shared__ __align__(16) unsigned short Vs[2][32][72];
    __shared__ __align__(16) unsigned short Ps[4][16][72];
    int tid = threadIdx.x;
    int wave = tid >> 6, lane = tid & 63;
    int ln = lane & 15, quad = lane >> 4;
    int qt = blockIdx.x, nh = blockIdx.y, kz = blockIdx.z;
    const unsigned short* Qg = qn + (size_t)nh * 73728;
    const unsigned short* Kg = kn + (size_t)nh * 73728;
    const unsigned short* Vg = vn + (size_t)nh * 73728;

    bf16x8 qf = *(const bf16x8*)(Qg + (size_t)(qt * 64 + wave * 16 + ln) * 32 + quad * 8);
    bf16x8 ones;
#pragma unroll
    for (int i = 0; i < 8; ++i) ones[i] = (short)0x3F80;

    f32x4 o0 = {0.f, 0.f, 0.f, 0.f};
    f32x4 o1 = {0.f, 0.f, 0.f, 0.f};
    f32x4 lac = {0.f, 0.f, 0.f, 0.f};

    int kt0 = kz * 12;
    uint4 kreg = *(const uint4*)(Kg + (size_t)(kt0 * 64) * 32 + tid * 8);
    uint4 vreg = *(const uint4*)(Vg + (size_t)(tid >> 3) * SEQ + kt0 * 64 + (tid & 7) * 8);
    *(uint4*)(&Ks[0][tid >> 2][(tid & 3) * 8]) = kreg;
    *(uint4*)(&Vs[0][tid >> 3][(tid & 7) * 8]) = vreg;

    for (int i = 0; i < 12; ++i) {
        int buf = i & 1;
        if (i + 1 < 12) {   // stage next tile into registers
            int k0n = (kt0 + i + 1) * 64;
            kreg = *(const uint4*)(Kg + (size_t)k0n * 32 + tid * 8);
            vreg = *(const uint4*)(Vg + (size_t)(tid >> 3) * SEQ + k0n + (tid & 7) * 8);
        }
        __syncthreads();   // buf fully written; prev-buf readers done

        const f32x4 zero = {0.f, 0.f, 0.f, 0.f};
#pragma unroll
        for (int c = 0; c < 4; ++c) {
            bf16x8 kf = *(const bf16x8*)(&Ks[buf][c * 16 + ln][quad * 8]);
            f32x4 sc = __builtin_amdgcn_mfma_f32_16x16x32_bf16(qf, kf, zero, 0, 0, 0);
#pragma unroll
            for (int r = 0; r < 4; ++r)
                Ps[wave][quad * 4 + r][c * 16 + ln] = f2bf(__expf(sc[r]));
        }
        // Ps is wave-private: lgkmcnt ordering suffices, no barrier
#pragma unroll
        for (int kc = 0; kc < 2; ++kc) {
            bf16x8 pf = *(const bf16x8*)(&Ps[wave][ln][kc * 32 + quad * 8]);
            bf16x8 v0 = *(const bf16x8*)(&Vs[buf][ln][kc * 32 + quad * 8]);
            bf16x8 v1 = *(const bf16x8*)(&Vs[buf][16 + ln][kc * 32 + quad * 8]);
            lac = __builtin_amdgcn_mfma_f32_16x16x32_bf16(pf, ones, lac, 0, 0, 0);
            o0  = __builtin_amdgcn_mfma_f32_16x16x32_bf16(pf, v0, o0, 0, 0, 0);
            o1  = __builtin_amdgcn_mfma_f32_16x16x32_bf16(pf, v1, o1, 0, 0, 0);
        }
        if (i + 1 < 12) {
            *(uint4*)(&Ks[buf ^ 1][tid >> 2][(tid & 3) * 8]) = kreg;
            *(uint4*)(&Vs[buf ^ 1][tid >> 3][(tid & 7) * 8]) = vreg;
        }
    }

    float* Ob = Opart + ((size_t)(kz * 16 + nh) * 36 + qt) * 2048;
    float* Lb = Lpart + ((size_t)(kz * 16 + nh) * 36 + qt) * 64;
#pragma unroll
    for (int r = 0; r < 4; ++r) {
        int ql = wave * 16 + quad * 4 + r;
        Ob[ql * 32 + ln]      = o0[r];
        Ob[ql * 32 + 16 + ln] = o1[r];
        if (ln == 0) Lb[ql] = lac[r];
    }
}

// ---------------- Kernel 4: split-K reduce -> y2t[n][s][c] bf16 ----------------
__global__ __launch_bounds__(256) void attn_reduce_kernel(const float* __restrict__ Opart,
                                                          const float* __restrict__ Lpart,
                                                          unsigned short* __restrict__ y2t) {
    int qt = blockIdx.x, nh = blockIdx.y;
    int n = nh >> 3, h = nh & 7;
    size_t s0 = (size_t)nh * 36 + qt;
    const float* O0 = Opart + s0 * 2048;
    const float* O1 = Opart + (s0 + 36 * 16) * 2048;
    const float* O2 = Opart + (s0 + 72 * 16) * 2048;
    const float* L0 = Lpart + s0 * 64;
    const float* L1 = Lpart + (s0 + 36 * 16) * 64;
    const float* L2 = Lpart + (s0 + 72 * 16) * 64;
#pragma unroll
    for (int p = 0; p < 8; ++p) {
        int idx = threadIdx.x + p * 256;
        int q = idx >> 5, c = idx & 31;
        float l = L0[q] + L1[q] + L2[q];
        float v = (O0[idx] + O1[idx] + O2[idx]) / l;
        y2t[((size_t)(n * SEQ) + qt * 64 + q) * 256 + h * 32 + c] = f2bf(v);
    }
}

// ---------------- Kernel 5: out GEMM (bf16 MFMA, LDS-free) + residual ----------------
__global__ __launch_bounds__(256) void out_gemm_kernel(const unsigned short* __restrict__ y2t,
                                                       const unsigned short* __restrict__ wob,
                                                       const float* __restrict__ x,
                                                       float* __restrict__ out) {
    int mt = blockIdx.x;   // 0..3
    int st = blockIdx.y;   // 0..35
    int n  = blockIdx.z;
    int tid = threadIdx.x;
    int wave = tid >> 6, lane = tid & 63;
    int ln = lane & 15, quad = lane >> 4;
    int m0 = mt * 64 + wave * 16;
    const unsigned short* Abase = wob + (size_t)(m0 + ln) * 256 + quad * 8;
    const unsigned short* Bbase = y2t + (size_t)(n * SEQ + st * 64 + ln) * 256 + quad * 8;
    f32x4 acc[4];
#pragma unroll
    for (int c = 0; c < 4; ++c) acc[c] = (f32x4){0.f, 0.f, 0.f, 0.f};
#pragma unroll
    for (int kc = 0; kc < 8; ++kc) {
        bf16x8 a = *(const bf16x8*)(Abase + kc * 32);
#pragma unroll
        for (int c = 0; c < 4; ++c) {
            bf16x8 b = *(const bf16x8*)(Bbase + (size_t)(c * 16) * 256 + kc * 32);
            acc[c] = __builtin_amdgcn_mfma_f32_16x16x32_bf16(a, b, acc[c], 0, 0, 0);
        }
    }
    const float c0f = 0.7f * 1.3130643285972254f;
    const float c1f = 0.3f * 1.3130643285972254f;
#pragma unroll
    for (int c = 0; c < 4; ++c)
#pragma unroll
        for (int r = 0; r < 4; ++r) {
            int o = m0 + quad * 4 + r;
            int s = st * 64 + c * 16 + ln;
            size_t idx = (size_t)(n * 256 + o) * SEQ + s;
            out[idx] = c0f * x[idx] + c1f * acc[c][r];
        }
}

extern "C" void kernel_launch(void* const* d_in, const int* in_sizes, int n_in,
                              void* d_out, int out_size, void* d_ws, size_t ws_size,
                              hipStream_t stream) {
    (void)in_sizes; (void)n_in; (void)out_size; (void)ws_size;
    const float* x     = (const float*)d_in[0];
    const float* w_qkv = (const float*)d_in[1];
    const float* w_out = (const float*)d_in[2];
    float* out = (float*)d_out;
    float* ws  = (float*)d_ws;
    // float offsets (same footprint as round 4, 24.6 MB):
    unsigned short* wqb = (unsigned short*)(ws);             // 98304 f
    unsigned short* wob = (unsigned short*)(ws + 98304);     // 32768 f
    unsigned short* xt  = (unsigned short*)(ws + 131072);    // 589824 f (dead after qkv)
    unsigned short* y2t = (unsigned short*)(ws + 131072);    // alias of xt
    unsigned short* qn  = (unsigned short*)(ws + 720896);
    unsigned short* kn  = (unsigned short*)(ws + 1310720);
    unsigned short* vn  = (unsigned short*)(ws + 1900544);
    float* Opart = ws + 2490368;                             // 48*36*2048 = 3538944 f
    float* Lpart = ws + 6029312;                             // 48*36*64   =  110592 f

    hipLaunchKernelGGL(prep_kernel, dim3(1312), dim3(256), 0, stream,
                       w_qkv, w_out, x, wqb, wob, xt);
    hipLaunchKernelGGL(qkv_fused_kernel, dim3(8, 36, 2), dim3(256), 0, stream,
                       xt, wqb, qn, kn, vn);
    hipLaunchKernelGGL(attn_mfma_kernel, dim3(36, 16, 3), dim3(256), 0, stream,
                       qn, kn, vn, Opart, Lpart);
    hipLaunchKernelGGL(attn_reduce_kernel, dim3(36, 16), dim3(256), 0, stream,
                       Opart, Lpart, y2t);
    hipLaunchKernelGGL(out_gemm_kernel, dim3(4, 36, 2), dim3(256), 0, stream,
                       y2t, wob, x, out);
}